// Round 3
// baseline (156.804 us; speedup 1.0000x reference)
//
#include <hip/hip_runtime.h>
#include <hip/hip_bf16.h>
#include <stdint.h>

#define IN_F 4096
#define OUT_F 11008
#define NUM_CH 128
#define NUM_NORM 3968
#define BATCH 64
#define KSPLIT 4
#define KCHUNK (IN_F / KSPLIT)   // 1024
#define NMEGA (KCHUNK / 128)     // 8 megasteps of K=128 per block
#define BS 136                   // LDS k-stride in shorts (16B-aligned)

typedef short short8 __attribute__((ext_vector_type(8)));
typedef float float4v __attribute__((ext_vector_type(4)));
typedef int int4v __attribute__((ext_vector_type(4)));

// Barrier WITHOUT the implicit s_waitcnt vmcnt(0) drain of __syncthreads().
// Waits only for this wave's own LDS ops (lgkmcnt); cross-wave LDS visibility
// is provided by the in-order DS pipe + the barrier. Global prefetch loads
// issued before this stay in flight across it.
__device__ __forceinline__ void barrier_no_vmcnt() {
    asm volatile("s_waitcnt lgkmcnt(0)\n\ts_barrier" ::: "memory");
}

__device__ __forceinline__ unsigned short f2bf(float f) {
    union { float f; unsigned u; } v; v.f = f;
    unsigned u = v.u;
    return (unsigned short)((u + 0x7FFFu + ((u >> 16) & 1u)) >> 16);
}

__device__ __forceinline__ unsigned pk_bf16(float lo, float hi) {
    __hip_bfloat162 h = __float22bfloat162_rn(make_float2(lo, hi));  // v_cvt_pk_bf16_f32
    union { __hip_bfloat162 h; unsigned u; } c; c.h = h; return c.u;
}

// Gather-permute x into bf16 xp[64][4096]
__global__ __launch_bounds__(256) void permute_x(
        const float* __restrict__ x, const int* __restrict__ cidx,
        unsigned short* __restrict__ xp) {
    int i = blockIdx.x * blockDim.x + threadIdx.x;
    int b = blockIdx.y;
    int lo = 0, hi = NUM_CH;
    while (lo < hi) { int mid = (lo + hi) >> 1; if (cidx[mid] < i) lo = mid + 1; else hi = mid; }
    bool isch = (lo < NUM_CH) && (cidx[lo] == i);
    int pos = isch ? (NUM_NORM + lo) : (i - lo);
    xp[b * IN_F + pos] = f2bf(x[b * IN_F + i]);
}

// out[m][n] = bias[n]  (overwrites harness poison; qgemm atomically adds partials)
__global__ __launch_bounds__(256) void init_out(
        const float* __restrict__ bias, float* __restrict__ out) {
    const int i = blockIdx.x * 256 + threadIdx.x;          // float4 index
    const int c = i % (OUT_F / 4);
    reinterpret_cast<float4v*>(out)[i] =
        *reinterpret_cast<const float4v*>(bias + c * 4);
}

// Fused dequant + bf16 MFMA GEMM. Same loop structure as round 2. ONLY
// change: the epilogue atomically accumulates into out[] directly
// (native global_atomic_add_f32 via unsafeAtomicAdd), eliminating the
// part[] buffer (11.25 MB write + 11.25 MB read) and the reduce_out kernel.
__global__ __launch_bounds__(256, 4) void qgemm(
        const unsigned short* __restrict__ xp, const int* __restrict__ qw,
        const float* __restrict__ cw, const float* __restrict__ scales,
        float* __restrict__ out) {
    __shared__ unsigned short Bt[2][64][BS];   // 2 x 17 KB

    const int tid  = threadIdx.x;
    const int wave = tid >> 6;
    const int lane = tid & 63;
    const int ln   = lane & 15;
    const int lq   = lane >> 4;
    const int n0    = blockIdx.x * 64;
    const int kbase = blockIdx.y * KCHUNK;
    const int tcol = (tid & 15) << 2;   // staging col offset 0..60
    const int trow = tid >> 4;          // staging row group 0..15

    const int*   qbase = qw + n0 + tcol;
    const float* sbase = scales + n0 + tcol;
    const float* cbase = cw + n0 + tcol;

    float4v acc[4];
    #pragma unroll
    for (int s = 0; s < 4; ++s) acc[s] = (float4v){0.f, 0.f, 0.f, 0.f};

    // ---- prologue: issue loads for megastep 0 (always normal region) ----
    int4v qcur[4]; float4v scur;
    {
        const int rb = (kbase >> 1) + 4 * trow;
        #pragma unroll
        for (int i = 0; i < 4; ++i)
            qcur[i] = *reinterpret_cast<const int4v*>(qbase + (size_t)(rb + i) * OUT_F);
        scur = *reinterpret_cast<const float4v*>(sbase + (size_t)(kbase >> 7) * OUT_F);
    }

    for (int s = 0; s < NMEGA; ++s) {
        const int k0 = kbase + s * 128;
        unsigned short (*buf)[BS] = Bt[s & 1];

        // ---- A-loads for THIS megastep, issued FIRST (before qw prefetch).
        // xp is L2-hot (512 KB); these return well before the MFMA phase.
        const unsigned short* xprow =
            xp + (size_t)((wave << 4) + ln) * IN_F + k0 + (lq << 3);
        const short8 a0 = *reinterpret_cast<const short8*>(xprow);
        const short8 a1 = *reinterpret_cast<const short8*>(xprow + 32);
        const short8 a2 = *reinterpret_cast<const short8*>(xprow + 64);
        const short8 a3 = *reinterpret_cast<const short8*>(xprow + 96);
        // Pin: the qw prefetch loads may not be scheduled above this point,
        // so the A-loads retire first in vmcnt order.
        __builtin_amdgcn_sched_barrier(0);

        if (k0 < NUM_NORM) {
            const int4v q0 = qcur[0], q1 = qcur[1], q2 = qcur[2], q3 = qcur[3];
            const float4v sc = scur;
            // prefetch next megastep's raw data — stays in flight through
            // the barrier AND the MFMA phase (A-loads retire first)
            const int kn = k0 + 128;
            if (s + 1 < NMEGA && kn < NUM_NORM) {
                const int rb = (kn >> 1) + 4 * trow;
                #pragma unroll
                for (int i = 0; i < 4; ++i)
                    qcur[i] = *reinterpret_cast<const int4v*>(qbase + (size_t)(rb + i) * OUT_F);
                scur = *reinterpret_cast<const float4v*>(sbase + (size_t)(kn >> 7) * OUT_F);
            }
            const int4v qq[4] = {q0, q1, q2, q3};
            #pragma unroll
            for (int cc = 0; cc < 4; ++cc) {
                union { short8 v; unsigned u[4]; } wv;
                const float s1 = sc[cc];
                #pragma unroll
                for (int i = 0; i < 4; ++i) {
                    const int q = qq[i][cc];
                    wv.u[i] = pk_bf16((float)((q & 0xF) - 8) * s1,
                                      (float)(((q >> 4) & 0xF) - 8) * s1);
                }
                *reinterpret_cast<short8*>(&buf[tcol + cc][trow * 8]) = wv.v;
            }
        } else {
            // pure-cherry megastep (k0 == NUM_NORM; only block ky==KSPLIT-1, s==NMEGA-1)
            float4v ch[8];
            #pragma unroll
            for (int j = 0; j < 8; ++j)
                ch[j] = *reinterpret_cast<const float4v*>(
                    cbase + (size_t)(8 * trow + j) * OUT_F);
            #pragma unroll
            for (int cc = 0; cc < 4; ++cc) {
                union { short8 v; unsigned u[4]; } wv;
                #pragma unroll
                for (int m = 0; m < 4; ++m)
                    wv.u[m] = pk_bf16(ch[2 * m][cc], ch[2 * m + 1][cc]);
                *reinterpret_cast<short8*>(&buf[tcol + cc][trow * 8]) = wv.v;
            }
        }

        barrier_no_vmcnt();   // orders LDS writes vs reads; leaves vmem in flight

        #pragma unroll
        for (int st = 0; st < 4; ++st) {
            const unsigned short* bp = &buf[(st << 4) + ln][lq << 3];
            acc[st] = __builtin_amdgcn_mfma_f32_16x16x32_bf16(
                a0, *reinterpret_cast<const short8*>(bp), acc[st], 0, 0, 0);
            acc[st] = __builtin_amdgcn_mfma_f32_16x16x32_bf16(
                a1, *reinterpret_cast<const short8*>(bp + 32), acc[st], 0, 0, 0);
            acc[st] = __builtin_amdgcn_mfma_f32_16x16x32_bf16(
                a2, *reinterpret_cast<const short8*>(bp + 64), acc[st], 0, 0, 0);
            acc[st] = __builtin_amdgcn_mfma_f32_16x16x32_bf16(
                a3, *reinterpret_cast<const short8*>(bp + 96), acc[st], 0, 0, 0);
        }
    }

    // Epilogue: atomic split-K accumulation straight into out[] (bias was
    // pre-broadcast by init_out). 4 ky-blocks hit each line; the 2.8 MB out
    // region stays cache-resident during accumulation.
    #pragma unroll
    for (int st = 0; st < 4; ++st) {
        const int n = n0 + (st << 4) + ln;
        #pragma unroll
        for (int r = 0; r < 4; ++r) {
            const int m = (wave << 4) + (lq << 2) + r;
            unsafeAtomicAdd(&out[(size_t)m * OUT_F + n], acc[st][r]);
        }
    }
}

extern "C" void kernel_launch(void* const* d_in, const int* in_sizes, int n_in,
                              void* d_out, int out_size, void* d_ws, size_t ws_size,
                              hipStream_t stream) {
    const float* x      = (const float*)d_in[0];
    const int*   qw     = (const int*)d_in[1];     // uint8 widened to int32 by harness
    const float* cw     = (const float*)d_in[2];
    const int*   cidx   = (const int*)d_in[3];
    const float* scales = (const float*)d_in[4];
    const float* bias   = (const float*)d_in[5];
    float*       out    = (float*)d_out;

    unsigned short* xp = (unsigned short*)d_ws;    // 512 KB (only ws use now)

    dim3 pgrid(IN_F / 256, BATCH);
    permute_x<<<pgrid, 256, 0, stream>>>(x, cidx, xp);
    init_out<<<(BATCH * OUT_F / 4) / 256, 256, 0, stream>>>(bias, out);
    qgemm<<<dim3(OUT_F / 64, KSPLIT), 256, 0, stream>>>(xp, qw, cw, scales, out);
}

// Round 4
// 156.162 us; speedup vs baseline: 1.0041x; 1.0041x over previous
//
#include <hip/hip_runtime.h>
#include <hip/hip_bf16.h>
#include <stdint.h>

#define IN_F 4096
#define OUT_F 11008
#define NUM_CH 128
#define NUM_NORM 3968
#define BATCH 64
#define KSPLIT 2
#define KCHUNK (IN_F / KSPLIT)   // 2048
#define NMEGA (KCHUNK / 128)     // 16 megasteps of K=128 per block
#define BS 136                   // LDS k-stride in shorts (16B-aligned)

typedef short short8 __attribute__((ext_vector_type(8)));
typedef float float4v __attribute__((ext_vector_type(4)));
typedef int int4v __attribute__((ext_vector_type(4)));

// Barrier WITHOUT the implicit s_waitcnt vmcnt(0) drain of __syncthreads().
// Waits only for this wave's own LDS ops (lgkmcnt); cross-wave LDS visibility
// is provided by the in-order DS pipe + the barrier. Global prefetch loads
// issued before this stay in flight across it.
__device__ __forceinline__ void barrier_no_vmcnt() {
    asm volatile("s_waitcnt lgkmcnt(0)\n\ts_barrier" ::: "memory");
}

__device__ __forceinline__ unsigned short f2bf(float f) {
    union { float f; unsigned u; } v; v.f = f;
    unsigned u = v.u;
    return (unsigned short)((u + 0x7FFFu + ((u >> 16) & 1u)) >> 16);
}

__device__ __forceinline__ unsigned pk_bf16(float lo, float hi) {
    __hip_bfloat162 h = __float22bfloat162_rn(make_float2(lo, hi));  // v_cvt_pk_bf16_f32
    union { __hip_bfloat162 h; unsigned u; } c; c.h = h; return c.u;
}

// Gather-permute x into bf16 xp[64][4096]
__global__ __launch_bounds__(256) void permute_x(
        const float* __restrict__ x, const int* __restrict__ cidx,
        unsigned short* __restrict__ xp) {
    int i = blockIdx.x * blockDim.x + threadIdx.x;
    int b = blockIdx.y;
    int lo = 0, hi = NUM_CH;
    while (lo < hi) { int mid = (lo + hi) >> 1; if (cidx[mid] < i) lo = mid + 1; else hi = mid; }
    bool isch = (lo < NUM_CH) && (cidx[lo] == i);
    int pos = isch ? (NUM_NORM + lo) : (i - lo);
    xp[b * IN_F + pos] = f2bf(x[b * IN_F + i]);
}

// out[m][n] = bias[n] + sum_ky part[ky][m][n]
__global__ __launch_bounds__(256) void reduce_out(
        const float* __restrict__ part, const float* __restrict__ bias,
        float* __restrict__ out) {
    const int i = blockIdx.x * 256 + threadIdx.x;          // float4 index
    const int c = i % (OUT_F / 4);
    float4v s = *reinterpret_cast<const float4v*>(bias + c * 4);
    #pragma unroll
    for (int ky = 0; ky < KSPLIT; ++ky) {
        const float4v p = reinterpret_cast<const float4v*>(
            part + (size_t)ky * BATCH * OUT_F)[i];
        s = (float4v){s[0] + p[0], s[1] + p[1], s[2] + p[2], s[3] + p[3]};
    }
    reinterpret_cast<float4v*>(out)[i] = s;
}

// Fused dequant + bf16 MFMA GEMM. Structure identical to the round-2 kernel
// (plain-store split-K partials; atomics reverted — they measured cost-neutral
// at best). ONLY change: KSPLIT 4->2 halves the part[] traffic again
// (11.25 MB total RW -> 5.6+5.6). Cherry boundary: 3968 = 2048 + 15*128, so
// the cherry megastep is exactly (ky==1, s==15) — path unchanged.
__global__ __launch_bounds__(256, 4) void qgemm(
        const unsigned short* __restrict__ xp, const int* __restrict__ qw,
        const float* __restrict__ cw, const float* __restrict__ scales,
        float* __restrict__ part) {
    __shared__ unsigned short Bt[2][64][BS];   // 2 x 17 KB

    const int tid  = threadIdx.x;
    const int wave = tid >> 6;
    const int lane = tid & 63;
    const int ln   = lane & 15;
    const int lq   = lane >> 4;
    const int n0    = blockIdx.x * 64;
    const int kbase = blockIdx.y * KCHUNK;
    const int tcol = (tid & 15) << 2;   // staging col offset 0..60
    const int trow = tid >> 4;          // staging row group 0..15

    const int*   qbase = qw + n0 + tcol;
    const float* sbase = scales + n0 + tcol;
    const float* cbase = cw + n0 + tcol;

    float4v acc[4];
    #pragma unroll
    for (int s = 0; s < 4; ++s) acc[s] = (float4v){0.f, 0.f, 0.f, 0.f};

    // ---- prologue: issue loads for megastep 0 (always normal region) ----
    int4v qcur[4]; float4v scur;
    {
        const int rb = (kbase >> 1) + 4 * trow;
        #pragma unroll
        for (int i = 0; i < 4; ++i)
            qcur[i] = *reinterpret_cast<const int4v*>(qbase + (size_t)(rb + i) * OUT_F);
        scur = *reinterpret_cast<const float4v*>(sbase + (size_t)(kbase >> 7) * OUT_F);
    }

    for (int s = 0; s < NMEGA; ++s) {
        const int k0 = kbase + s * 128;
        unsigned short (*buf)[BS] = Bt[s & 1];

        // ---- A-loads for THIS megastep, issued FIRST (before qw prefetch).
        // xp is L2-hot (512 KB); these return well before the MFMA phase.
        const unsigned short* xprow =
            xp + (size_t)((wave << 4) + ln) * IN_F + k0 + (lq << 3);
        const short8 a0 = *reinterpret_cast<const short8*>(xprow);
        const short8 a1 = *reinterpret_cast<const short8*>(xprow + 32);
        const short8 a2 = *reinterpret_cast<const short8*>(xprow + 64);
        const short8 a3 = *reinterpret_cast<const short8*>(xprow + 96);
        // Pin: the qw prefetch loads may not be scheduled above this point,
        // so the A-loads retire first in vmcnt order.
        __builtin_amdgcn_sched_barrier(0);

        if (k0 < NUM_NORM) {
            const int4v q0 = qcur[0], q1 = qcur[1], q2 = qcur[2], q3 = qcur[3];
            const float4v sc = scur;
            // prefetch next megastep's raw data — stays in flight through
            // the barrier AND the MFMA phase (A-loads retire first)
            const int kn = k0 + 128;
            if (s + 1 < NMEGA && kn < NUM_NORM) {
                const int rb = (kn >> 1) + 4 * trow;
                #pragma unroll
                for (int i = 0; i < 4; ++i)
                    qcur[i] = *reinterpret_cast<const int4v*>(qbase + (size_t)(rb + i) * OUT_F);
                scur = *reinterpret_cast<const float4v*>(sbase + (size_t)(kn >> 7) * OUT_F);
            }
            const int4v qq[4] = {q0, q1, q2, q3};
            #pragma unroll
            for (int cc = 0; cc < 4; ++cc) {
                union { short8 v; unsigned u[4]; } wv;
                const float s1 = sc[cc];
                #pragma unroll
                for (int i = 0; i < 4; ++i) {
                    const int q = qq[i][cc];
                    wv.u[i] = pk_bf16((float)((q & 0xF) - 8) * s1,
                                      (float)(((q >> 4) & 0xF) - 8) * s1);
                }
                *reinterpret_cast<short8*>(&buf[tcol + cc][trow * 8]) = wv.v;
            }
        } else {
            // pure-cherry megastep (k0 == NUM_NORM; only block ky==KSPLIT-1, s==NMEGA-1)
            float4v ch[8];
            #pragma unroll
            for (int j = 0; j < 8; ++j)
                ch[j] = *reinterpret_cast<const float4v*>(
                    cbase + (size_t)(8 * trow + j) * OUT_F);
            #pragma unroll
            for (int cc = 0; cc < 4; ++cc) {
                union { short8 v; unsigned u[4]; } wv;
                #pragma unroll
                for (int m = 0; m < 4; ++m)
                    wv.u[m] = pk_bf16(ch[2 * m][cc], ch[2 * m + 1][cc]);
                *reinterpret_cast<short8*>(&buf[tcol + cc][trow * 8]) = wv.v;
            }
        }

        barrier_no_vmcnt();   // orders LDS writes vs reads; leaves vmem in flight

        #pragma unroll
        for (int st = 0; st < 4; ++st) {
            const unsigned short* bp = &buf[(st << 4) + ln][lq << 3];
            acc[st] = __builtin_amdgcn_mfma_f32_16x16x32_bf16(
                a0, *reinterpret_cast<const short8*>(bp), acc[st], 0, 0, 0);
            acc[st] = __builtin_amdgcn_mfma_f32_16x16x32_bf16(
                a1, *reinterpret_cast<const short8*>(bp + 32), acc[st], 0, 0, 0);
            acc[st] = __builtin_amdgcn_mfma_f32_16x16x32_bf16(
                a2, *reinterpret_cast<const short8*>(bp + 64), acc[st], 0, 0, 0);
            acc[st] = __builtin_amdgcn_mfma_f32_16x16x32_bf16(
                a3, *reinterpret_cast<const short8*>(bp + 96), acc[st], 0, 0, 0);
        }
    }

    // Epilogue: plain partial stores. part[ky][m][n].
    float* pbase = part + (size_t)blockIdx.y * BATCH * OUT_F;
    #pragma unroll
    for (int st = 0; st < 4; ++st) {
        const int n = n0 + (st << 4) + ln;
        #pragma unroll
        for (int r = 0; r < 4; ++r) {
            const int m = (wave << 4) + (lq << 2) + r;
            pbase[(size_t)m * OUT_F + n] = acc[st][r];
        }
    }
}

extern "C" void kernel_launch(void* const* d_in, const int* in_sizes, int n_in,
                              void* d_out, int out_size, void* d_ws, size_t ws_size,
                              hipStream_t stream) {
    const float* x      = (const float*)d_in[0];
    const int*   qw     = (const int*)d_in[1];     // uint8 widened to int32 by harness
    const float* cw     = (const float*)d_in[2];
    const int*   cidx   = (const int*)d_in[3];
    const float* scales = (const float*)d_in[4];
    const float* bias   = (const float*)d_in[5];
    float*       out    = (float*)d_out;

    unsigned short* xp   = (unsigned short*)d_ws;                    // 512 KB
    float*          part = (float*)((char*)d_ws + (512 << 10));      // 5.6 MB

    dim3 pgrid(IN_F / 256, BATCH);
    permute_x<<<pgrid, 256, 0, stream>>>(x, cidx, xp);
    qgemm<<<dim3(OUT_F / 64, KSPLIT), 256, 0, stream>>>(xp, qw, cw, scales, part);
    reduce_out<<<(BATCH * OUT_F / 4) / 256, 256, 0, stream>>>(part, bias, out);
}